// Round 1
// baseline (328.175 us; speedup 1.0000x reference)
//
#include <hip/hip_runtime.h>
#include <hip/hip_bf16.h>
#include <stdint.h>

#define S_LEN 2048
#define DM 1024
#define NH 16
#define HD 64

typedef __bf16 bf16x8 __attribute__((ext_vector_type(8)));
typedef float f32x4 __attribute__((ext_vector_type(4)));
typedef unsigned short u16x4 __attribute__((ext_vector_type(4)));

#if __has_builtin(__builtin_amdgcn_exp2f)
#define EXP2F(x) __builtin_amdgcn_exp2f(x)
#else
#define EXP2F(x) exp2f(x)
#endif

__device__ __forceinline__ unsigned short f2bf(float f){
  union { float f; uint32_t u; } v; v.f = f;
  uint32_t r = v.u + 0x7fffu + ((v.u >> 16) & 1u);
  return (unsigned short)(r >> 16);
}

__device__ __forceinline__ void load_lds16(const void* g, void* l){
  __builtin_amdgcn_global_load_lds((const __attribute__((address_space(1))) void*)g,
                                   (__attribute__((address_space(3))) void*)l, 16, 0, 0);
}

__device__ __forceinline__ f32x4 mfma16(bf16x8 a, bf16x8 b, f32x4 c){
  return __builtin_amdgcn_mfma_f32_16x16x32_bf16(a, b, c, 0, 0, 0);
}

// rows are 64 bf16 = 128B; swizzle byte_off ^= ((row&7)<<4) to break the 128B-stride bank conflict
__device__ __forceinline__ bf16x8 lds_swz_read(const unsigned short* base, int row, int cb){
  int addr = (row << 7) + (cb ^ ((row & 7) << 4));
  return *reinterpret_cast<const bf16x8*>(reinterpret_cast<const char*>(base) + addr);
}

// ---------------- prep: f32 -> bf16 for x and the 4 weight matrices ----------------
__global__ void prep_kernel(const float* __restrict__ x,
                            const float* __restrict__ wq, const float* __restrict__ wk,
                            const float* __restrict__ wv, const float* __restrict__ wo,
                            unsigned short* __restrict__ ws_base){
  long idx = ((long)blockIdx.x * 256 + threadIdx.x) * 4;
  const float* s; unsigned short* d; long off;
  if (idx < (1L << 22)) { s = x; d = ws_base; off = idx; }
  else {
    long r = idx - (1L << 22);
    int wsel = (int)(r >> 20);
    off = r & ((1L << 20) - 1);
    s = wsel == 0 ? wq : wsel == 1 ? wk : wsel == 2 ? wv : wo;
    d = ws_base + (1L << 22) + ((long)wsel << 20);
  }
  float4 f = *reinterpret_cast<const float4*>(s + off);
  u16x4 o;
  o[0] = f2bf(f.x); o[1] = f2bf(f.y); o[2] = f2bf(f.z); o[3] = f2bf(f.w);
  *reinterpret_cast<u16x4*>(d + off) = o;
}

// ---------------- GEMM: C = A[M,1024] * B[N,1024]^T + bias ----------------
// MODE 0: fused QKV (A = x_bf16). grid.x = 24: nb>>3 selects Q/K/V. Q,K stored [B,H,S,64]; V stored [B,H,64,S].
// MODE 1: output projection (A = ctx_bf16), f32 flat output.
template<int MODE>
__global__ __launch_bounds__(256, 2)
void gemm_bt_kernel(const unsigned short* __restrict__ A,
                    const unsigned short* __restrict__ B0,
                    const unsigned short* __restrict__ B1,
                    const unsigned short* __restrict__ B2,
                    const float* __restrict__ bias0,
                    const float* __restrict__ bias1,
                    const float* __restrict__ bias2,
                    unsigned short* __restrict__ q_out,
                    unsigned short* __restrict__ k_out,
                    unsigned short* __restrict__ vt_out,
                    float* __restrict__ f_out)
{
  __shared__ unsigned short As[128 * 64];
  __shared__ unsigned short Bs[128 * 64];
  const int tid = threadIdx.x;
  const int lane = tid & 63;
  const int w = tid >> 6;
  const int wr = w >> 1, wc = w & 1;
  const int mBase = blockIdx.y * 128;
  int nb = blockIdx.x;
  const unsigned short* Bmat; const float* bias; int mat;
  if constexpr (MODE == 0) {
    mat = nb >> 3;
    nb &= 7;
    Bmat = mat == 0 ? B0 : (mat == 1 ? B1 : B2);
    bias = mat == 0 ? bias0 : (mat == 1 ? bias1 : bias2);
  } else { mat = 0; Bmat = B0; bias = bias0; }
  const int nBase = nb * 128;

  f32x4 acc[4][4] = {};
  const int srow = lane >> 3;                 // row within 8-row chunk
  const int ksrc = ((lane & 7) ^ srow) * 8;   // pre-swizzled source k-offset (elements)
  const unsigned short* ArowBase = A    + (size_t)(mBase + w * 32 + srow) * DM + ksrc;
  const unsigned short* BrowBase = Bmat + (size_t)(nBase + w * 32 + srow) * DM + ksrc;

  for (int kt = 0; kt < 16; ++kt) {
    #pragma unroll
    for (int i = 0; i < 4; ++i) {
      load_lds16(ArowBase + (size_t)(i * 8) * DM + kt * 64, &As[(w * 4 + i) * 512]);
      load_lds16(BrowBase + (size_t)(i * 8) * DM + kt * 64, &Bs[(w * 4 + i) * 512]);
    }
    __syncthreads();
    #pragma unroll
    for (int kk = 0; kk < 2; ++kk) {
      bf16x8 af[4], bfr[4];
      const int cb = kk * 64 + ((lane >> 4) << 4);
      #pragma unroll
      for (int m = 0; m < 4; ++m)
        af[m] = lds_swz_read(As, wr * 64 + m * 16 + (lane & 15), cb);
      #pragma unroll
      for (int n = 0; n < 4; ++n)
        bfr[n] = lds_swz_read(Bs, wc * 64 + n * 16 + (lane & 15), cb);
      #pragma unroll
      for (int m = 0; m < 4; ++m)
        #pragma unroll
        for (int n = 0; n < 4; ++n)
          acc[m][n] = mfma16(af[m], bfr[n], acc[m][n]);
    }
    __syncthreads();
  }

  // epilogue: bias + store
  #pragma unroll
  for (int m = 0; m < 4; ++m) {
    #pragma unroll
    for (int n = 0; n < 4; ++n) {
      const int col = nBase + wc * 64 + n * 16 + (lane & 15);
      const float bv = bias[col];
      const int row0 = mBase + wr * 64 + m * 16 + ((lane >> 4) << 2);
      if constexpr (MODE == 1) {
        #pragma unroll
        for (int j = 0; j < 4; ++j)
          f_out[(size_t)(row0 + j) * DM + col] = acc[m][n][j] + bv;
      } else {
        const int h = col >> 6, d = col & 63;
        if (mat < 2) {
          unsigned short* dst = (mat == 0) ? q_out : k_out;
          #pragma unroll
          for (int j = 0; j < 4; ++j) {
            const int row = row0 + j;
            const int b = row >> 11, s = row & 2047;
            dst[(((size_t)b * NH + h) * S_LEN + s) * HD + d] = f2bf(acc[m][n][j] + bv);
          }
        } else {
          const int b = row0 >> 11, s = row0 & 2047;
          u16x4 pk;
          #pragma unroll
          for (int j = 0; j < 4; ++j) pk[j] = f2bf(acc[m][n][j] + bv);
          *reinterpret_cast<u16x4*>(&vt_out[(((size_t)b * NH + h) * HD + d) * S_LEN + s]) = pk;
        }
      }
    }
  }
}

// ---------------- flash attention ----------------
// grid = (B=2, 32 q-tiles, 16 heads); block = 256 (4 waves x 16 q-rows); KV tile = 64
__global__ __launch_bounds__(256, 2)
void attn_kernel(const unsigned short* __restrict__ Q,
                 const unsigned short* __restrict__ Kmat,
                 const unsigned short* __restrict__ Vt,
                 const float* __restrict__ rel_bias,
                 const float* __restrict__ mask,
                 unsigned short* __restrict__ ctx)
{
  __shared__ unsigned short Ks[64 * 64];
  __shared__ unsigned short Vs[64 * 64];
  __shared__ unsigned short Ps[4][16 * 64];
  const int b = blockIdx.x, qt = blockIdx.y, h = blockIdx.z;
  const int lane = threadIdx.x & 63, w = threadIdx.x >> 6;
  const size_t bh = (size_t)b * NH + h;
  const int qRow = qt * 64 + w * 16;
  const unsigned short* Qp = Q + (bh * S_LEN + qRow) * HD;
  bf16x8 qf0, qf1;
  {
    const int r = lane & 15, k = (lane >> 4) * 8;
    qf0 = *reinterpret_cast<const bf16x8*>(Qp + (size_t)r * HD + k);
    qf1 = *reinterpret_cast<const bf16x8*>(Qp + (size_t)r * HD + 32 + k);
  }
  const unsigned short* Kp = Kmat + bh * (size_t)S_LEN * HD;
  const unsigned short* Vp = Vt + bh * (size_t)HD * S_LEN;
  const float* bp = rel_bias + (size_t)h * S_LEN * S_LEN;

  float m_run[4], l_run[4];
  f32x4 acc[4] = {};
  #pragma unroll
  for (int j = 0; j < 4; ++j) { m_run[j] = -3.0e38f; l_run[j] = 0.f; }

  const float SC  = 0.125f * 1.44269504089f;  // scale * log2(e): softmax done in exp2 domain
  const float L2E = 1.44269504089f;

  const int srow = lane >> 3;
  const int ksrc = ((lane & 7) ^ srow) * 8;

  for (int kt = 0; kt < 32; ++kt) {
    const int kvBase = kt * 64;
    #pragma unroll
    for (int i = 0; i < 2; ++i) {
      const int chunk = w * 2 + i;
      const int row = chunk * 8 + srow;
      load_lds16(Kp + (size_t)(kvBase + row) * HD + ksrc, &Ks[chunk * 512]);
      load_lds16(Vp + (size_t)row * S_LEN + kvBase + ksrc, &Vs[chunk * 512]);
    }
    __syncthreads();

    // QK^T: C-layout rows = local q-row, cols = key
    f32x4 sc[4];
    const int cbq = (lane >> 4) << 4;
    #pragma unroll
    for (int n = 0; n < 4; ++n) {
      const int row = n * 16 + (lane & 15);
      bf16x8 kf0 = lds_swz_read(Ks, row, cbq);
      bf16x8 kf1 = lds_swz_read(Ks, row, 64 + cbq);
      f32x4 z = {};
      z = mfma16(qf0, kf0, z);
      sc[n] = mfma16(qf1, kf1, z);
    }

    // add rel_bias + mask, convert to log2 domain
    float t[4][4];
    #pragma unroll
    for (int n = 0; n < 4; ++n) {
      const int kg = kvBase + n * 16 + (lane & 15);
      #pragma unroll
      for (int j = 0; j < 4; ++j) {
        const int qg = qRow + ((lane >> 4) << 2) + j;
        const float bm = bp[(size_t)qg * S_LEN + kg] + mask[(size_t)qg * S_LEN + kg];
        t[n][j] = sc[n][j] * SC + bm * L2E;
      }
    }

    // online softmax (16-lane row groups)
    #pragma unroll
    for (int j = 0; j < 4; ++j) {
      float mt = fmaxf(fmaxf(t[0][j], t[1][j]), fmaxf(t[2][j], t[3][j]));
      mt = fmaxf(mt, __shfl_xor(mt, 1));
      mt = fmaxf(mt, __shfl_xor(mt, 2));
      mt = fmaxf(mt, __shfl_xor(mt, 4));
      mt = fmaxf(mt, __shfl_xor(mt, 8));
      const float mn = fmaxf(m_run[j], mt);
      const float corr = EXP2F(m_run[j] - mn);
      m_run[j] = mn;
      float ls = 0.f;
      #pragma unroll
      for (int n = 0; n < 4; ++n) {
        const float p = EXP2F(t[n][j] - mn);
        t[n][j] = p;
        ls += p;
      }
      ls += __shfl_xor(ls, 1);
      ls += __shfl_xor(ls, 2);
      ls += __shfl_xor(ls, 4);
      ls += __shfl_xor(ls, 8);
      l_run[j] = l_run[j] * corr + ls;
      #pragma unroll
      for (int n = 0; n < 4; ++n) acc[n][j] *= corr;
    }

    // write P (bf16) to per-wave swizzled LDS, reread as A-fragments
    unsigned short* Pw = Ps[w];
    #pragma unroll
    for (int n = 0; n < 4; ++n) {
      #pragma unroll
      for (int j = 0; j < 4; ++j) {
        const int row = ((lane >> 4) << 2) + j;
        const int cbw = (n * 16 + (lane & 15)) * 2;
        *reinterpret_cast<unsigned short*>(
            reinterpret_cast<char*>(Pw) + (row << 7) + (cbw ^ ((row & 7) << 4))) = f2bf(t[n][j]);
      }
    }
    bf16x8 pf0, pf1;
    {
      const int r = lane & 15;
      pf0 = lds_swz_read(Pw, r, cbq);
      pf1 = lds_swz_read(Pw, r, 64 + cbq);
    }
    #pragma unroll
    for (int n = 0; n < 4; ++n) {
      const int row = n * 16 + (lane & 15);
      bf16x8 vf0 = lds_swz_read(Vs, row, cbq);
      bf16x8 vf1 = lds_swz_read(Vs, row, 64 + cbq);
      acc[n] = mfma16(pf0, vf0, acc[n]);
      acc[n] = mfma16(pf1, vf1, acc[n]);
    }
    __syncthreads();
  }

  // epilogue: normalize, store ctx [B,S,DM] bf16
  unsigned short* cp = ctx + ((size_t)b * S_LEN + qRow) * DM + h * HD;
  #pragma unroll
  for (int j = 0; j < 4; ++j) {
    const float inv = 1.0f / l_run[j];
    const int row = ((lane >> 4) << 2) + j;
    #pragma unroll
    for (int n = 0; n < 4; ++n)
      cp[(size_t)row * DM + n * 16 + (lane & 15)] = f2bf(acc[n][j] * inv);
  }
}

extern "C" void kernel_launch(void* const* d_in, const int* in_sizes, int n_in,
                              void* d_out, int out_size, void* d_ws, size_t ws_size,
                              hipStream_t stream) {
  (void)in_sizes; (void)n_in; (void)out_size; (void)ws_size;
  const float* x  = (const float*)d_in[0];
  const float* rb = (const float*)d_in[1];
  const float* mk = (const float*)d_in[2];
  const float* Wq = (const float*)d_in[3];
  const float* bq = (const float*)d_in[4];
  const float* Wk = (const float*)d_in[5];
  const float* bk = (const float*)d_in[6];
  const float* Wv = (const float*)d_in[7];
  const float* bv = (const float*)d_in[8];
  const float* Wo = (const float*)d_in[9];
  const float* bo = (const float*)d_in[10];
  float* out = (float*)d_out;

  unsigned short* ws  = (unsigned short*)d_ws;
  unsigned short* xb  = ws;                       // 4M elems
  unsigned short* wqb = ws + (1L << 22);          // 1M
  unsigned short* wkb = wqb + (1L << 20);
  unsigned short* wvb = wkb + (1L << 20);
  unsigned short* wob = wvb + (1L << 20);
  unsigned short* Qw  = wob + (1L << 20);         // 4M [B,H,S,64]
  unsigned short* Kw  = Qw + (1L << 22);          // 4M [B,H,S,64]
  unsigned short* Vtw = Kw + (1L << 22);          // 4M [B,H,64,S]
  unsigned short* ctx = Vtw + (1L << 22);         // 4M [B,S,DM]

  prep_kernel<<<8192, 256, 0, stream>>>(x, Wq, Wk, Wv, Wo, ws);
  gemm_bt_kernel<0><<<dim3(24, 32), 256, 0, stream>>>(
      xb, wqb, wkb, wvb, bq, bk, bv, Qw, Kw, Vtw, nullptr);
  attn_kernel<<<dim3(2, 32, 16), 256, 0, stream>>>(Qw, Kw, Vtw, rb, mk, ctx);
  gemm_bt_kernel<1><<<dim3(8, 32), 256, 0, stream>>>(
      ctx, wob, nullptr, nullptr, bo, nullptr, nullptr, nullptr, nullptr, nullptr, out);
}

// Round 2
// 256.914 us; speedup vs baseline: 1.2774x; 1.2774x over previous
//
#include <hip/hip_runtime.h>
#include <hip/hip_bf16.h>
#include <stdint.h>

#define S_LEN 2048
#define DM 1024
#define NH 16
#define HD 64

typedef __bf16 bf16x8 __attribute__((ext_vector_type(8)));
typedef float f32x4 __attribute__((ext_vector_type(4)));
typedef unsigned short u16x4 __attribute__((ext_vector_type(4)));

#if __has_builtin(__builtin_amdgcn_exp2f)
#define EXP2F(x) __builtin_amdgcn_exp2f(x)
#else
#define EXP2F(x) exp2f(x)
#endif

__device__ __forceinline__ unsigned short f2bf(float f){
  union { float f; uint32_t u; } v; v.f = f;
  uint32_t r = v.u + 0x7fffu + ((v.u >> 16) & 1u);
  return (unsigned short)(r >> 16);
}

__device__ __forceinline__ void load_lds16(const void* g, void* l){
  __builtin_amdgcn_global_load_lds((const __attribute__((address_space(1))) void*)g,
                                   (__attribute__((address_space(3))) void*)l, 16, 0, 0);
}

__device__ __forceinline__ f32x4 mfma16(bf16x8 a, bf16x8 b, f32x4 c){
  return __builtin_amdgcn_mfma_f32_16x16x32_bf16(a, b, c, 0, 0, 0);
}

// rows are 64 bf16 = 128B; swizzle byte_off ^= ((row&7)<<4) to break the 128B-stride bank conflict
__device__ __forceinline__ bf16x8 lds_swz_read(const unsigned short* base, int row, int cb){
  int addr = (row << 7) + (cb ^ ((row & 7) << 4));
  return *reinterpret_cast<const bf16x8*>(reinterpret_cast<const char*>(base) + addr);
}

// ---------------- prep: f32 -> bf16 for x and the 4 weight matrices ----------------
__global__ void prep_kernel(const float* __restrict__ x,
                            const float* __restrict__ wq, const float* __restrict__ wk,
                            const float* __restrict__ wv, const float* __restrict__ wo,
                            unsigned short* __restrict__ ws_base){
  long idx = ((long)blockIdx.x * 256 + threadIdx.x) * 4;
  const float* s; unsigned short* d; long off;
  if (idx < (1L << 22)) { s = x; d = ws_base; off = idx; }
  else {
    long r = idx - (1L << 22);
    int wsel = (int)(r >> 20);
    off = r & ((1L << 20) - 1);
    s = wsel == 0 ? wq : wsel == 1 ? wk : wsel == 2 ? wv : wo;
    d = ws_base + (1L << 22) + ((long)wsel << 20);
  }
  float4 f = *reinterpret_cast<const float4*>(s + off);
  u16x4 o;
  o[0] = f2bf(f.x); o[1] = f2bf(f.y); o[2] = f2bf(f.z); o[3] = f2bf(f.w);
  *reinterpret_cast<u16x4*>(d + off) = o;
}

// ---------------- GEMM: C = A[M,1024] * B[N,1024]^T + bias ----------------
// MODE 0: fused QKV (A = x_bf16). grid.x = 24: nb>>3 selects Q/K/V. Q,K stored [B,H,S,64]; V stored [B,H,64,S].
// MODE 1: output projection (A = ctx_bf16), f32 flat output.
template<int MODE>
__global__ __launch_bounds__(256, 2)
void gemm_bt_kernel(const unsigned short* __restrict__ A,
                    const unsigned short* __restrict__ B0,
                    const unsigned short* __restrict__ B1,
                    const unsigned short* __restrict__ B2,
                    const float* __restrict__ bias0,
                    const float* __restrict__ bias1,
                    const float* __restrict__ bias2,
                    unsigned short* __restrict__ q_out,
                    unsigned short* __restrict__ k_out,
                    unsigned short* __restrict__ vt_out,
                    float* __restrict__ f_out)
{
  __shared__ unsigned short As[128 * 64];
  __shared__ unsigned short Bs[128 * 64];
  const int tid = threadIdx.x;
  const int lane = tid & 63;
  const int w = tid >> 6;
  const int wr = w >> 1, wc = w & 1;
  const int mBase = blockIdx.y * 128;
  int nb = blockIdx.x;
  const unsigned short* Bmat; const float* bias; int mat;
  if constexpr (MODE == 0) {
    mat = nb >> 3;
    nb &= 7;
    Bmat = mat == 0 ? B0 : (mat == 1 ? B1 : B2);
    bias = mat == 0 ? bias0 : (mat == 1 ? bias1 : bias2);
  } else { mat = 0; Bmat = B0; bias = bias0; }
  const int nBase = nb * 128;

  f32x4 acc[4][4] = {};
  const int srow = lane >> 3;                 // row within 8-row chunk
  const int ksrc = ((lane & 7) ^ srow) * 8;   // pre-swizzled source k-offset (elements)
  const unsigned short* ArowBase = A    + (size_t)(mBase + w * 32 + srow) * DM + ksrc;
  const unsigned short* BrowBase = Bmat + (size_t)(nBase + w * 32 + srow) * DM + ksrc;

  for (int kt = 0; kt < 16; ++kt) {
    #pragma unroll
    for (int i = 0; i < 4; ++i) {
      load_lds16(ArowBase + (size_t)(i * 8) * DM + kt * 64, &As[(w * 4 + i) * 512]);
      load_lds16(BrowBase + (size_t)(i * 8) * DM + kt * 64, &Bs[(w * 4 + i) * 512]);
    }
    __syncthreads();
    #pragma unroll
    for (int kk = 0; kk < 2; ++kk) {
      bf16x8 af[4], bfr[4];
      const int cb = kk * 64 + ((lane >> 4) << 4);
      #pragma unroll
      for (int m = 0; m < 4; ++m)
        af[m] = lds_swz_read(As, wr * 64 + m * 16 + (lane & 15), cb);
      #pragma unroll
      for (int n = 0; n < 4; ++n)
        bfr[n] = lds_swz_read(Bs, wc * 64 + n * 16 + (lane & 15), cb);
      #pragma unroll
      for (int m = 0; m < 4; ++m)
        #pragma unroll
        for (int n = 0; n < 4; ++n)
          acc[m][n] = mfma16(af[m], bfr[n], acc[m][n]);
    }
    __syncthreads();
  }

  // epilogue: bias + store
  #pragma unroll
  for (int m = 0; m < 4; ++m) {
    #pragma unroll
    for (int n = 0; n < 4; ++n) {
      const int col = nBase + wc * 64 + n * 16 + (lane & 15);
      const float bv = bias[col];
      const int row0 = mBase + wr * 64 + m * 16 + ((lane >> 4) << 2);
      if constexpr (MODE == 1) {
        #pragma unroll
        for (int j = 0; j < 4; ++j)
          f_out[(size_t)(row0 + j) * DM + col] = acc[m][n][j] + bv;
      } else {
        const int h = col >> 6, d = col & 63;
        if (mat < 2) {
          unsigned short* dst = (mat == 0) ? q_out : k_out;
          #pragma unroll
          for (int j = 0; j < 4; ++j) {
            const int row = row0 + j;
            const int b = row >> 11, s = row & 2047;
            dst[(((size_t)b * NH + h) * S_LEN + s) * HD + d] = f2bf(acc[m][n][j] + bv);
          }
        } else {
          const int b = row0 >> 11, s = row0 & 2047;
          u16x4 pk;
          #pragma unroll
          for (int j = 0; j < 4; ++j) pk[j] = f2bf(acc[m][n][j] + bv);
          *reinterpret_cast<u16x4*>(&vt_out[(((size_t)b * NH + h) * HD + d) * S_LEN + s]) = pk;
        }
      }
    }
  }
}

// ---------------- flash attention (transposed-score form) ----------------
// grid = (B=2, 32 q-tiles, 16 heads); block = 256 (4 waves x 16 q-rows); KV tile = 64
// Scores computed transposed: sc = mfma(K,Q) so lane holds 4 CONSECUTIVE k at fixed
// q=lane&15 -> bias/mask load as float4; softmax m/l are per-lane scalars.
// PV computed as ctx^T = Vt * P^T so corr/normalize stay per-lane uniform.
__global__ __launch_bounds__(256, 4)
void attn_kernel(const unsigned short* __restrict__ Q,
                 const unsigned short* __restrict__ Kmat,
                 const unsigned short* __restrict__ Vt,
                 const float* __restrict__ rel_bias,
                 const float* __restrict__ mask,
                 unsigned short* __restrict__ ctx)
{
  __shared__ unsigned short Ks[2][64 * 64];
  __shared__ unsigned short Vs[2][64 * 64];
  __shared__ unsigned short Ps[4][16 * 64];
  const int b = blockIdx.x, qt = blockIdx.y, h = blockIdx.z;
  const int lane = threadIdx.x & 63, w = threadIdx.x >> 6;
  const int q = lane & 15, g = lane >> 4;
  const size_t bh = (size_t)b * NH + h;
  const int qRow = qt * 64 + w * 16;
  const unsigned short* Qp = Q + (bh * S_LEN + qRow) * HD;
  bf16x8 qf0 = *reinterpret_cast<const bf16x8*>(Qp + (size_t)q * HD + g * 8);
  bf16x8 qf1 = *reinterpret_cast<const bf16x8*>(Qp + (size_t)q * HD + 32 + g * 8);

  const unsigned short* Kp = Kmat + bh * (size_t)S_LEN * HD;
  const unsigned short* Vp = Vt + bh * (size_t)HD * S_LEN;
  const float* bp = rel_bias + (size_t)h * S_LEN * S_LEN + (size_t)(qRow + q) * S_LEN;
  const float* mp = mask + (size_t)(qRow + q) * S_LEN;

  float m_run = -3.0e38f, l_run = 0.f;
  f32x4 acc[4] = {};

  const float SC  = 0.125f * 1.44269504089f;  // head scale * log2(e)
  const float L2E = 1.44269504089f;

  const int srow = lane >> 3;
  const int ksrc = ((lane & 7) ^ srow) * 8;   // pre-swizzled global k-offset

  // prologue: stage tile 0 into buffer 0
  #pragma unroll
  for (int i = 0; i < 2; ++i) {
    const int chunk = w * 2 + i;
    const int row = chunk * 8 + srow;
    load_lds16(Kp + (size_t)row * HD + ksrc, &Ks[0][chunk * 512]);
    load_lds16(Vp + (size_t)row * S_LEN + ksrc, &Vs[0][chunk * 512]);
  }
  __syncthreads();

  for (int kt = 0; kt < 32; ++kt) {
    const int cur = kt & 1;
    const int kvBase = kt * 64;

    // bias + mask vector loads for THIS tile (issued before stage so the
    // compiler's counted vmcnt for their use does not drain the stage)
    float4 b4[4], m4[4];
    #pragma unroll
    for (int n = 0; n < 4; ++n) {
      b4[n] = *reinterpret_cast<const float4*>(bp + kvBase + n * 16 + g * 4);
      m4[n] = *reinterpret_cast<const float4*>(mp + kvBase + n * 16 + g * 4);
    }

    // stage NEXT tile into the other buffer; overlaps with this tile's compute
    if (kt < 31) {
      const int nb = kvBase + 64;
      #pragma unroll
      for (int i = 0; i < 2; ++i) {
        const int chunk = w * 2 + i;
        const int row = chunk * 8 + srow;
        load_lds16(Kp + (size_t)(nb + row) * HD + ksrc, &Ks[cur ^ 1][chunk * 512]);
        load_lds16(Vp + (size_t)row * S_LEN + nb + ksrc, &Vs[cur ^ 1][chunk * 512]);
      }
    }

    // QK^T (transposed): sc[n] holds scores^T[k = kvBase + n*16 + 4g + j][q]
    f32x4 sc[4];
    const int cbq = g << 4;
    #pragma unroll
    for (int n = 0; n < 4; ++n) {
      const int row = n * 16 + q;
      bf16x8 kf0 = lds_swz_read(Ks[cur], row, cbq);
      bf16x8 kf1 = lds_swz_read(Ks[cur], row, 64 + cbq);
      f32x4 z = {};
      z = mfma16(kf0, qf0, z);
      sc[n] = mfma16(kf1, qf1, z);
    }

    // to exp2 domain with bias + mask
    float t[4][4];
    float mt = -3.0e38f;
    #pragma unroll
    for (int n = 0; n < 4; ++n) {
      #pragma unroll
      for (int j = 0; j < 4; ++j) {
        const float bm = ((const float*)&b4[n])[j] + ((const float*)&m4[n])[j];
        const float fv = sc[n][j] * SC + bm * L2E;
        t[n][j] = fv;
        mt = fmaxf(mt, fv);
      }
    }
    // row max across the 4 lane-groups holding this q
    mt = fmaxf(mt, __shfl_xor(mt, 16));
    mt = fmaxf(mt, __shfl_xor(mt, 32));
    const float mn = fmaxf(m_run, mt);
    const float corr = EXP2F(m_run - mn);
    m_run = mn;
    float ls = 0.f;
    #pragma unroll
    for (int n = 0; n < 4; ++n)
      #pragma unroll
      for (int j = 0; j < 4; ++j) {
        const float p = EXP2F(t[n][j] - mn);
        t[n][j] = p;
        ls += p;
      }
    ls += __shfl_xor(ls, 16);
    ls += __shfl_xor(ls, 32);
    l_run = l_run * corr + ls;
    #pragma unroll
    for (int n = 0; n < 4; ++n) acc[n] *= corr;

    // P^T frag -> LDS [q][k] layout, 8B swizzled writes (4 consecutive k per write)
    unsigned short* Pw = Ps[w];
    #pragma unroll
    for (int n = 0; n < 4; ++n) {
      u16x4 pk;
      #pragma unroll
      for (int j = 0; j < 4; ++j) pk[j] = f2bf(t[n][j]);
      const int colb = (n * 16 + 4 * g) * 2;
      *reinterpret_cast<u16x4*>(
          reinterpret_cast<char*>(Pw) + (q << 7) + (colb ^ ((q & 7) << 4))) = pk;
    }
    // P as B-fragment: row q, k-major
    bf16x8 pf0 = lds_swz_read(Pw, q, cbq);
    bf16x8 pf1 = lds_swz_read(Pw, q, 64 + cbq);
    // ctx^T[d][q] += Vt * P^T
    #pragma unroll
    for (int n = 0; n < 4; ++n) {
      bf16x8 vf0 = lds_swz_read(Vs[cur], n * 16 + q, cbq);
      bf16x8 vf1 = lds_swz_read(Vs[cur], n * 16 + q, 64 + cbq);
      acc[n] = mfma16(vf0, pf0, acc[n]);
      acc[n] = mfma16(vf1, pf1, acc[n]);
    }
    __syncthreads();
  }

  // epilogue: normalize, redistribute through per-wave LDS, coalesced 16B stores
  const float inv = 1.0f / l_run;
  unsigned short* Pw = Ps[w];
  #pragma unroll
  for (int n = 0; n < 4; ++n) {
    u16x4 pk;
    #pragma unroll
    for (int j = 0; j < 4; ++j) pk[j] = f2bf(acc[n][j] * inv);
    const int colb = (n * 16 + 4 * g) * 2;
    *reinterpret_cast<u16x4*>(
        reinterpret_cast<char*>(Pw) + (q << 7) + (colb ^ ((q & 7) << 4))) = pk;
  }
  bf16x8 c0 = lds_swz_read(Pw, q, g << 4);
  bf16x8 c1 = lds_swz_read(Pw, q, 64 + (g << 4));
  unsigned short* cp = ctx + ((size_t)b * S_LEN + qRow + q) * DM + h * HD;
  *reinterpret_cast<bf16x8*>(cp + 8 * g) = c0;
  *reinterpret_cast<bf16x8*>(cp + 32 + 8 * g) = c1;
}

extern "C" void kernel_launch(void* const* d_in, const int* in_sizes, int n_in,
                              void* d_out, int out_size, void* d_ws, size_t ws_size,
                              hipStream_t stream) {
  (void)in_sizes; (void)n_in; (void)out_size; (void)ws_size;
  const float* x  = (const float*)d_in[0];
  const float* rb = (const float*)d_in[1];
  const float* mk = (const float*)d_in[2];
  const float* Wq = (const float*)d_in[3];
  const float* bq = (const float*)d_in[4];
  const float* Wk = (const float*)d_in[5];
  const float* bk = (const float*)d_in[6];
  const float* Wv = (const float*)d_in[7];
  const float* bv = (const float*)d_in[8];
  const float* Wo = (const float*)d_in[9];
  const float* bo = (const float*)d_in[10];
  float* out = (float*)d_out;

  unsigned short* ws  = (unsigned short*)d_ws;
  unsigned short* xb  = ws;                       // 4M elems
  unsigned short* wqb = ws + (1L << 22);          // 1M
  unsigned short* wkb = wqb + (1L << 20);
  unsigned short* wvb = wkb + (1L << 20);
  unsigned short* wob = wvb + (1L << 20);
  unsigned short* Qw  = wob + (1L << 20);         // 4M [B,H,S,64]
  unsigned short* Kw  = Qw + (1L << 22);          // 4M [B,H,S,64]
  unsigned short* Vtw = Kw + (1L << 22);          // 4M [B,H,64,S]
  unsigned short* ctx = Vtw + (1L << 22);         // 4M [B,S,DM]

  prep_kernel<<<8192, 256, 0, stream>>>(x, Wq, Wk, Wv, Wo, ws);
  gemm_bt_kernel<0><<<dim3(24, 32), 256, 0, stream>>>(
      xb, wqb, wkb, wvb, bq, bk, bv, Qw, Kw, Vtw, nullptr);
  attn_kernel<<<dim3(2, 32, 16), 256, 0, stream>>>(Qw, Kw, Vtw, rb, mk, ctx);
  gemm_bt_kernel<1><<<dim3(8, 32), 256, 0, stream>>>(
      ctx, wob, nullptr, nullptr, bo, nullptr, nullptr, nullptr, nullptr, nullptr, out);
}